// Round 1
// baseline (1796.052 us; speedup 1.0000x reference)
//
#include <hip/hip_runtime.h>

#define BT 2      // batch rows per block
#define NC 24     // C_IN
#define NH 32     // HIDDEN

struct Params {
  const float* x[6];
  const float* W[6];
  const float* cg;
  float* out;
};

// ---- pair tables (order matches reference: l1 outer asc, l2 inner asc) ----
constexpr int NPAIRS_C[6] = {6, 15, 21, 24, 24, 21};
constexpr int POFF_C[6]   = {0, 6, 21, 42, 66, 90};

__constant__ int c_l1[111] = {
  0,1,2,3,4,5,
  0,1,1,1,2,2,2,3,3,3,4,4,4,5,5,
  0,1,1,1,2,2,2,2,2,3,3,3,3,3,4,4,4,4,5,5,5,
  0,1,1,1,2,2,2,2,2,3,3,3,3,3,3,4,4,4,4,4,5,5,5,5,
  0,1,1,1,2,2,2,2,3,3,3,3,3,4,4,4,4,4,4,5,5,5,5,5,
  0,1,1,2,2,2,3,3,3,3,4,4,4,4,4,5,5,5,5,5,5
};
__constant__ int c_l2[111] = {
  0,1,2,3,4,5,
  1,0,1,2,1,2,3,2,3,4,3,4,5,4,5,
  2,1,2,3,0,1,2,3,4,1,2,3,4,5,2,3,4,5,3,4,5,
  3,2,3,4,1,2,3,4,5,0,1,2,3,4,5,1,2,3,4,5,2,3,4,5,
  4,3,4,5,2,3,4,5,1,2,3,4,5,0,1,2,3,4,5,1,2,3,4,5,
  5,4,5,3,4,5,2,3,4,5,1,2,3,4,5,0,1,2,3,4,5
};
__constant__ int c_off[6] = {0, 6, 21, 42, 66, 90};

// ---- LDS layout (float offsets) ----
#define X1_OFF 0          // [BT][24][16] = 768
#define X2_OFF 768        // [BT][24][16] = 768
#define CG_OFF 1536       // 1331 (+pad to 1344)
#define PS_OFF 2880       // [BT*M][576], max 22*576 = 12672
#define SMEM_FLOATS 15552 // 62208 bytes

// Fully-unrolled CG term loop. cg slice is zero where i>=2*l1+1 or j>=2*l2+1,
// so summing all (i,j) with valid m is exact (x rows are zero-padded too).
template<int L, int K0>
__device__ __forceinline__ void cg_terms(const float* __restrict__ cgs,
                                         const float (&x1r)[12],
                                         const float (&x2a)[12],
                                         const float (&x2b)[12],
                                         float (&pa)[2*L+1], float (&pb)[2*L+1]) {
#pragma unroll
  for (int i = 0; i < 11; ++i) {
#pragma unroll
    for (int j = 0; j < 11; ++j) {
      const int m = i + j - K0;   // constant-folded after unroll
      if (m >= 0 && m < 2*L+1) {
        float cgv = cgs[m*121 + i*11 + j];
        float tt = cgv * x1r[i];
        pa[m] += tt * x2a[j];
        pb[m] += tt * x2b[j];
      }
    }
  }
}

template<int L>
__device__ __forceinline__ void cg_terms_dispatch(int K0, const float* __restrict__ cgs,
    const float (&x1r)[12], const float (&x2a)[12], const float (&x2b)[12],
    float (&pa)[2*L+1], float (&pb)[2*L+1]) {
  switch (K0) {
    case 0:  cg_terms<L,0 >(cgs,x1r,x2a,x2b,pa,pb); break;
    case 1:  cg_terms<L,1 >(cgs,x1r,x2a,x2b,pa,pb); break;
    case 2:  cg_terms<L,2 >(cgs,x1r,x2a,x2b,pa,pb); break;
    case 3:  cg_terms<L,3 >(cgs,x1r,x2a,x2b,pa,pb); break;
    case 4:  cg_terms<L,4 >(cgs,x1r,x2a,x2b,pa,pb); break;
    case 5:  cg_terms<L,5 >(cgs,x1r,x2a,x2b,pa,pb); break;
    case 6:  cg_terms<L,6 >(cgs,x1r,x2a,x2b,pa,pb); break;
    case 7:  cg_terms<L,7 >(cgs,x1r,x2a,x2b,pa,pb); break;
    case 8:  cg_terms<L,8 >(cgs,x1r,x2a,x2b,pa,pb); break;
    case 9:  cg_terms<L,9 >(cgs,x1r,x2a,x2b,pa,pb); break;
    default: cg_terms<L,10>(cgs,x1r,x2a,x2b,pa,pb); break;
  }
}

template<int L>
__device__ __forceinline__ void body(const Params& P) {
  constexpr int M   = 2*L + 1;
  constexpr int NP  = NPAIRS_C[L];
  constexpr int KL  = NP * 576;       // K of this l's GEMM
  constexpr int BTM = BT * M;         // p rows per block (even)
  constexpr int RS  = (BTM + 3) / 4;  // row-sets per lane in GEMM

  extern __shared__ float smem[];
  float* x1s = smem + X1_OFF;
  float* x2s = smem + X2_OFF;
  float* cgs = smem + CG_OFF;
  float* ps  = smem + PS_OFF;

  const int t    = threadIdx.x;
  const int lane = t & 63;
  const int w    = t >> 6;     // wave id: owns h in [8w, 8w+8)
  const int kg   = lane & 15;  // k-group
  const int r4   = lane >> 4;  // row-group
  const int b0   = blockIdx.y * BT;

  float acc[RS][8];
#pragma unroll
  for (int a = 0; a < RS; ++a)
#pragma unroll
    for (int h = 0; h < 8; ++h) acc[a][h] = 0.f;

  const int off = c_off[L];
  const float* __restrict__ Wl = P.W[L];

  for (int pi = 0; pi < NP; ++pi) {
    const int l1 = c_l1[off + pi], l2 = c_l2[off + pi];
    const int n1 = 2*l1 + 1, n2 = 2*l2 + 1;
    const float* __restrict__ xg1 = P.x[l1];
    const float* __restrict__ xg2 = P.x[l2];
    const float* __restrict__ cgp = P.cg + (size_t)((l1*6 + l2)*6 + L) * 1331;

    // ---- A: stage x1, x2 (zero-padded rows, stride 16) and cg slice ----
    for (int e = t; e < BT*NC*16; e += 256) {
      int bt = e / (NC*16), r = e % (NC*16), c = r >> 4, i = r & 15;
      x1s[e] = (i < n1) ? xg1[((b0 + bt)*NC + c)*n1 + i] : 0.f;
    }
    for (int e = t; e < BT*NC*16; e += 256) {
      int bt = e / (NC*16), r = e % (NC*16), c = r >> 4, i = r & 15;
      x2s[e] = (i < n2) ? xg2[((b0 + bt)*NC + c)*n2 + i] : 0.f;
    }
    for (int e = t; e < 1331; e += 256) cgs[e] = cgp[e];
    __syncthreads();  // stage done; also orders prev GEMM's ps reads before new ps writes

    // ---- B: p tile. thread = (bt, c, d0), computes d0 and d0+12, all m ----
    const int K0 = l1 + l2 - L;
    for (int g = t; g < BT*288; g += 256) {
      int bt = g / 288, r = g % 288, c = r / 12, d0 = r % 12;
      float x1r[12], x2a[12], x2b[12];
      const float4* q1 = (const float4*)&x1s[(bt*NC + c)*16];
      const float4* qa = (const float4*)&x2s[(bt*NC + d0)*16];
      const float4* qb = (const float4*)&x2s[(bt*NC + d0 + 12)*16];
      *(float4*)&x1r[0] = q1[0]; *(float4*)&x1r[4] = q1[1]; *(float4*)&x1r[8] = q1[2];
      *(float4*)&x2a[0] = qa[0]; *(float4*)&x2a[4] = qa[1]; *(float4*)&x2a[8] = qa[2];
      *(float4*)&x2b[0] = qb[0]; *(float4*)&x2b[4] = qb[1]; *(float4*)&x2b[8] = qb[2];
      float pa[M], pb[M];
#pragma unroll
      for (int m = 0; m < M; ++m) { pa[m] = 0.f; pb[m] = 0.f; }
      cg_terms_dispatch<L>(K0, cgs, x1r, x2a, x2b, pa, pb);
#pragma unroll
      for (int m = 0; m < M; ++m) {
        ps[(bt*M + m)*576 + c*24 + d0]      = pa[m];
        ps[(bt*M + m)*576 + c*24 + d0 + 12] = pb[m];
      }
    }
    __syncthreads();  // ps ready

    // ---- C: GEMM accumulate. wave owns 8 h's -> each W element loaded once/block ----
    const float* __restrict__ wb = Wl + pi * 576;
#pragma unroll
    for (int it = 0; it < 9; ++it) {
      const int k4 = kg + 16*it;  // float4 index in [0,144)
      float4 wv[8];
#pragma unroll
      for (int h8 = 0; h8 < 8; ++h8)
        wv[h8] = *(const float4*)&wb[(size_t)(8*w + h8)*KL + 4*k4];
#pragma unroll
      for (int rs = 0; rs < RS; ++rs) {
        const int row = r4 + 4*rs;
        if (row < BTM) {
          float4 pv = *(const float4*)&ps[row*576 + 4*k4];
#pragma unroll
          for (int h8 = 0; h8 < 8; ++h8) {
            acc[rs][h8] += wv[h8].x*pv.x + wv[h8].y*pv.y
                         + wv[h8].z*pv.z + wv[h8].w*pv.w;
          }
        }
      }
    }
    // no sync needed here: next stage writes x/cg (disjoint from ps);
    // next ps write is ordered by the sync after staging.
  }

  // ---- reduce k-partials across the 16 kg lanes, then store ----
#pragma unroll
  for (int rs = 0; rs < RS; ++rs) {
    const int row = r4 + 4*rs;  // btm = bt*M + m
#pragma unroll
    for (int h8 = 0; h8 < 8; ++h8) {
      float v = acc[rs][h8];
      v += __shfl_xor(v, 1);
      v += __shfl_xor(v, 2);
      v += __shfl_xor(v, 4);
      v += __shfl_xor(v, 8);
      if (kg == 0 && row < BTM) {
        int bt = row / M, m = row % M;
        int h = 8*w + h8;
        P.out[(size_t)(b0 + bt)*(NH*36) + h*36 + L*L + m] = v;
      }
    }
  }
}

__global__ __launch_bounds__(256)
void CGLayer_kernel(Params P) {
  switch (blockIdx.x) {
    case 0: body<0>(P); break;
    case 1: body<1>(P); break;
    case 2: body<2>(P); break;
    case 3: body<3>(P); break;
    case 4: body<4>(P); break;
    default: body<5>(P); break;
  }
}

extern "C" void kernel_launch(void* const* d_in, const int* in_sizes, int n_in,
                              void* d_out, int out_size, void* d_ws, size_t ws_size,
                              hipStream_t stream) {
  Params P;
  for (int i = 0; i < 6; ++i) P.x[i] = (const float*)d_in[i];
  for (int i = 0; i < 6; ++i) P.W[i] = (const float*)d_in[6 + i];
  P.cg  = (const float*)d_in[12];
  P.out = (float*)d_out;

  dim3 grid(6, 256 / BT, 1);  // x = l (fast-varying for CU mixing), y = b-tile
  CGLayer_kernel<<<grid, 256, SMEM_FLOATS * sizeof(float), stream>>>(P);
}

// Round 2
// 202.421 us; speedup vs baseline: 8.8728x; 8.8728x over previous
//
#include <hip/hip_runtime.h>
#include <hip/hip_bf16.h>

#define NC 24
#define BT 16

typedef __attribute__((ext_vector_type(8))) short bf16x8;
typedef __attribute__((ext_vector_type(4))) float f32x4;

struct Params {
  const float* x[6];
  const float* W[6];
  const float* cg;
  float* out;
  unsigned short* Wb;   // ws: W pre-swizzled to bf16 B-fragment order (4,091,904 B)
};

constexpr int NPAIRS_C[6] = {6, 15, 21, 24, 24, 21};
constexpr int POFF_C[6]   = {0, 6, 21, 42, 66, 90};
constexpr size_t WBASE_C[6] = {0, 110592, 387072, 774144, 1216512, 1658880};

__constant__ int c_l1[111] = {
  0,1,2,3,4,5,
  0,1,1,1,2,2,2,3,3,3,4,4,4,5,5,
  0,1,1,1,2,2,2,2,2,3,3,3,3,3,4,4,4,4,5,5,5,
  0,1,1,1,2,2,2,2,2,3,3,3,3,3,3,4,4,4,4,4,5,5,5,5,
  0,1,1,1,2,2,2,2,3,3,3,3,3,4,4,4,4,4,4,5,5,5,5,5,
  0,1,1,2,2,2,3,3,3,3,4,4,4,4,4,5,5,5,5,5,5
};
__constant__ int c_l2[111] = {
  0,1,2,3,4,5,
  1,0,1,2,1,2,3,2,3,4,3,4,5,4,5,
  2,1,2,3,0,1,2,3,4,1,2,3,4,5,2,3,4,5,3,4,5,
  3,2,3,4,1,2,3,4,5,0,1,2,3,4,5,1,2,3,4,5,2,3,4,5,
  4,3,4,5,2,3,4,5,1,2,3,4,5,0,1,2,3,4,5,1,2,3,4,5,
  5,4,5,3,4,5,2,3,4,5,1,2,3,4,5,0,1,2,3,4,5
};
// (l, m') blocks ordered heavy-l first for dispatch balance
__constant__ int c_mb_l[36] = {3,3,3,3,3,3,3, 4,4,4,4,4,4,4,4,4, 5,5,5,5,5,5,5,5,5,5,5, 2,2,2,2,2, 1,1,1, 0};
__constant__ int c_mb_m[36] = {0,1,2,3,4,5,6, 0,1,2,3,4,5,6,7,8, 0,1,2,3,4,5,6,7,8,9,10, 0,1,2,3,4, 0,1,2, 0};
__constant__ int c_KL[6]  = {3456, 8640, 12096, 13824, 13824, 12096};
__constant__ int c_bW8[6] = {0, 13824, 48384, 96768, 152064, 207360};

// ---------- W swizzle: fp32 [h][k] -> bf16 B-fragment stream ----------
// element(l,pair,chunk,hh,lane,e) = W_l[16*hh + (lane&15)][pair*576 + chunk*32 + (lane>>4)*8 + e]
__global__ __launch_bounds__(256)
void swizzle_W(Params P) {
  const int u = blockIdx.x * 256 + threadIdx.x;   // [0, 255744), 8 elements each
  int l = 0;
#pragma unroll
  for (int q = 1; q < 6; ++q) l += (u >= c_bW8[q]) ? 1 : 0;
  const int r8 = u - c_bW8[l];
  const int lane = r8 & 63;
  int q2 = r8 >> 6;
  const int hh = q2 & 1; q2 >>= 1;
  const int kc = q2 % 18;
  const int pair = q2 / 18;
  const int h = hh * 16 + (lane & 15);
  const int k = kc * 32 + (lane >> 4) * 8;
  const float* src = P.W[l] + (size_t)h * c_KL[l] + pair * 576 + k;
  f32x4 v0 = *(const f32x4*)src;
  f32x4 v1 = *(const f32x4*)(src + 4);
  union BF2U { __hip_bfloat162 h; unsigned int u; } z;
  unsigned int o0, o1, o2, o3;
  z.h = __float22bfloat162_rn(make_float2(v0.x, v0.y)); o0 = z.u;
  z.h = __float22bfloat162_rn(make_float2(v0.z, v0.w)); o1 = z.u;
  z.h = __float22bfloat162_rn(make_float2(v1.x, v1.y)); o2 = z.u;
  z.h = __float22bfloat162_rn(make_float2(v1.z, v1.w)); o3 = z.u;
  ((uint4*)P.Wb)[u] = make_uint4(o0, o1, o2, o3);
}

// ---------- LDS layout (bytes) ----------
#define XS1_B 0          // [16][11][24] f32 = 16896
#define XS2_B 16896      // [16][11][24] f32 = 16896
#define PB_B  33792      // [16][584] bf16 = 18688 (row stride 584: word-stride%32==4, 16B aligned)
#define CGD_B 52480      // [11] f32
#define SMEM_BYTES 52544 // 3 blocks/CU (157,632 <= 163,840)

template<int L>
__device__ __forceinline__ void body(const Params& P, const int mp, const int btile) {
  constexpr int NP = NPAIRS_C[L];
  constexpr int OFF = POFF_C[L];
  extern __shared__ char smem[];
  float* xs1 = (float*)(smem + XS1_B);
  float* xs2 = (float*)(smem + XS2_B);
  unsigned short* Pb = (unsigned short*)(smem + PB_B);
  float* cgd = (float*)(smem + CGD_B);
  float* red = (float*)(smem + PB_B);   // alias Pb after final GEMM: [4][16][32] f32

  const int t = threadIdx.x;
  const int lane = t & 63;
  const int w = t >> 6;
  const int b0 = btile * BT;

  f32x4 acc0 = {0.f, 0.f, 0.f, 0.f}, acc1 = {0.f, 0.f, 0.f, 0.f};

  // p-compute item: thread = (b, c-triple, d-half); exactly 256 items
  const int p_dh = t & 1;
  const int p_ct = (t >> 1) & 7;
  const int p_b  = t >> 4;
  const int p_d0 = p_dh * 12;
  const int p_c0 = p_ct * 3;

  // A-fragment base: lane holds P[b = lane&15][k = (lane>>4)*8 + e]
  const unsigned short* pb_frag = Pb + (lane & 15) * 584 + (lane >> 4) * 8;

  int prev_l1 = -1, prev_l2 = -1;

  for (int pi = 0; pi < NP; ++pi) {
    const int l1 = c_l1[OFF + pi], l2 = c_l2[OFF + pi];
    const int n1 = 2 * l1 + 1, n2 = 2 * l2 + 1;
    const int mK0 = mp + l1 + l2 - L;

    // ---- stage x transposed: xs[(b*11 + i)*24 + c] (skip if same l as prev pair) ----
    if (l1 != prev_l1) {
      const float* s1 = P.x[l1] + (size_t)b0 * NC * n1;
      for (int i = 0; i < n1; ++i)
        for (int e = t; e < BT * NC; e += 256) {
          int b = e / NC, c = e % NC;
          xs1[(b * 11 + i) * 24 + c] = s1[e * n1 + i];
        }
    }
    if (l2 != prev_l2) {
      const float* s2 = P.x[l2] + (size_t)b0 * NC * n2;
      for (int i = 0; i < n2; ++i)
        for (int e = t; e < BT * NC; e += 256) {
          int b = e / NC, c = e % NC;
          xs2[(b * 11 + i) * 24 + c] = s2[e * n2 + i];
        }
    }
    prev_l1 = l1; prev_l2 = l2;

    // ---- stage CG diagonal for this m' ----
    if (t < 11) {
      int i = t, j = mK0 - i;
      float v = 0.f;
      if (i < n1 && j >= 0 && j < n2)
        v = P.cg[(size_t)((((l1 * 6 + l2) * 6 + L) * 11 + mp) * 11 + i) * 11 + j];
      cgd[i] = v;
    }
    __syncthreads();   // staging ready; prev GEMM done reading Pb

    // ---- p-compute: p[b, c0..c0+2, d0..d0+11] for this m' ----
    {
      const int lo = mK0 - (n2 - 1);
      const int i0 = lo > 0 ? lo : 0;
      const int i1 = (n1 - 1) < mK0 ? (n1 - 1) : mK0;
      float p[3][12];
#pragma unroll
      for (int q = 0; q < 3; ++q)
#pragma unroll
        for (int d = 0; d < 12; ++d) p[q][d] = 0.f;

      const float* x1b = &xs1[(p_b * 11) * 24 + p_c0];
      const float* x2b = &xs2[(p_b * 11) * 24 + p_d0];
      for (int i = i0; i <= i1; ++i) {
        const float cgv = cgd[i];
        const float* xr = x2b + (mK0 - i) * 24;
        float xv[12];
        *(f32x4*)&xv[0] = *(const f32x4*)xr;
        *(f32x4*)&xv[4] = *(const f32x4*)(xr + 4);
        *(f32x4*)&xv[8] = *(const f32x4*)(xr + 8);
#pragma unroll
        for (int q = 0; q < 3; ++q) {
          const float t1 = cgv * x1b[i * 24 + q];
#pragma unroll
          for (int d = 0; d < 12; ++d) p[q][d] += t1 * xv[d];
        }
      }
      // pack bf16 and store to Pb[b][k = c*24 + d]
#pragma unroll
      for (int q = 0; q < 3; ++q) {
        unsigned int uu[6];
#pragma unroll
        for (int d2 = 0; d2 < 6; ++d2) {
          union { __hip_bfloat162 h; unsigned int u; } z;
          z.h = __float22bfloat162_rn(make_float2(p[q][2 * d2], p[q][2 * d2 + 1]));
          uu[d2] = z.u;
        }
        uint2* dst = (uint2*)&Pb[p_b * 584 + (p_c0 + q) * 24 + p_d0];
        dst[0] = make_uint2(uu[0], uu[1]);
        dst[1] = make_uint2(uu[2], uu[3]);
        dst[2] = make_uint2(uu[4], uu[5]);
      }
    }
    __syncthreads();   // Pb ready

    // ---- MFMA GEMM: wave w handles k-chunks kc % 4 == w, both h-halves ----
    {
      const unsigned short* wbp = P.Wb + WBASE_C[L] + (size_t)pi * 18432 + lane * 8;
      for (int kc = w; kc < 18; kc += 4) {
        bf16x8 af = *(const bf16x8*)(pb_frag + kc * 32);
        bf16x8 wf0 = *(const bf16x8*)(wbp + kc * 1024);
        bf16x8 wf1 = *(const bf16x8*)(wbp + kc * 1024 + 512);
        acc0 = __builtin_amdgcn_mfma_f32_16x16x32_bf16(af, wf0, acc0, 0, 0, 0);
        acc1 = __builtin_amdgcn_mfma_f32_16x16x32_bf16(af, wf1, acc1, 0, 0, 0);
      }
    }
  }

  __syncthreads();   // all GEMM reads of Pb done; red aliases Pb
  {
    const int n = lane & 15, g4 = lane >> 4;
#pragma unroll
    for (int r = 0; r < 4; ++r) {           // C/D: col=lane&15, row=(lane>>4)*4+reg
      red[(w * 16 + g4 * 4 + r) * 32 + n] = acc0[r];
      red[(w * 16 + g4 * 4 + r) * 32 + 16 + n] = acc1[r];
    }
  }
  __syncthreads();
#pragma unroll
  for (int it = 0; it < 2; ++it) {
    const int idx = t + 256 * it;           // 512 outputs: 16 b x 32 h
    const int b = idx >> 5, h = idx & 31;
    float v = red[b * 32 + h] + red[512 + b * 32 + h]
            + red[1024 + b * 32 + h] + red[1536 + b * 32 + h];
    P.out[(size_t)(b0 + b) * 1152 + h * 36 + L * L + mp] = v;
  }
}

__global__ __launch_bounds__(256, 3)
void CGLayer_main(Params P) {
  const int mb = blockIdx.x;
  const int l = c_mb_l[mb], mp = c_mb_m[mb];
  const int btile = blockIdx.y;
  switch (l) {
    case 0: body<0>(P, mp, btile); break;
    case 1: body<1>(P, mp, btile); break;
    case 2: body<2>(P, mp, btile); break;
    case 3: body<3>(P, mp, btile); break;
    case 4: body<4>(P, mp, btile); break;
    default: body<5>(P, mp, btile); break;
  }
}

extern "C" void kernel_launch(void* const* d_in, const int* in_sizes, int n_in,
                              void* d_out, int out_size, void* d_ws, size_t ws_size,
                              hipStream_t stream) {
  Params P;
  for (int i = 0; i < 6; ++i) P.x[i] = (const float*)d_in[i];
  for (int i = 0; i < 6; ++i) P.W[i] = (const float*)d_in[6 + i];
  P.cg  = (const float*)d_in[12];
  P.out = (float*)d_out;
  P.Wb  = (unsigned short*)d_ws;   // needs 4,091,904 bytes

  swizzle_W<<<999, 256, 0, stream>>>(P);
  dim3 grid(36, 16);
  CGLayer_main<<<grid, 256, SMEM_BYTES, stream>>>(P);
}